// Round 11
// baseline (136.817 us; speedup 1.0000x reference)
//
#include <hip/hip_runtime.h>
#include <hip/hip_bf16.h>

#define BS   8
#define TT   1024
#define DIN  64
#define NH   8
#define DOUT 1024

typedef __attribute__((ext_vector_type(8))) short bf16x8;
typedef __attribute__((ext_vector_type(8))) unsigned short u16x8;
typedef __attribute__((ext_vector_type(4))) float f32x4;
typedef __attribute__((ext_vector_type(2))) float f32x2;

typedef __attribute__((address_space(3))) unsigned int lds_u32;
typedef const __attribute__((address_space(1))) unsigned int glb_u32;

__device__ __forceinline__ unsigned short f2bf(float f) {
    unsigned int u = __float_as_uint(f);
    u += 0x7fff + ((u >> 16) & 1);          // RNE
    return (unsigned short)(u >> 16);
}

__device__ __forceinline__ f32x2 pk_fma(f32x2 a, f32x2 b, f32x2 c) {
    f32x2 d;
    asm("v_pk_fma_f32 %0, %1, %2, %3" : "=v"(d) : "v"(a), "v"(b), "v"(c));
    return d;
}
__device__ __forceinline__ f32x2 pk_add(f32x2 a, f32x2 b) {
    f32x2 d;
    asm("v_pk_add_f32 %0, %1, %2" : "=v"(d) : "v"(a), "v"(b));
    return d;
}

// ---------------- Kernel A: fused prep ----------------
// blocks 0..1023   : qk projection (8 rows each)
// blocks 1024..1151: X -> XtP packed-fragment bf16 transpose
// blocks 1152..2175: W_w -> bf16
__global__ __launch_bounds__(256) void prep_fused(const float* __restrict__ X,
                                                  const float* __restrict__ Wq_w,
                                                  const float* __restrict__ Wq_b,
                                                  const float* __restrict__ Wk_w,
                                                  const float* __restrict__ Wk_b,
                                                  const float* __restrict__ W_w,
                                                  float* __restrict__ Q,
                                                  float* __restrict__ K,
                                                  unsigned short* __restrict__ XtP,
                                                  unsigned short* __restrict__ Wbf) {
    __shared__ float Ws[32][65];
    __shared__ float bsm[32];
    __shared__ float Xs[8][64];
    __shared__ unsigned short S[64][68];

    const int bid = blockIdx.x, tid = threadIdx.x;

    if (bid < 1024) {
        // ---- qk projection ----
        for (int i = tid; i < 2048; i += 256) {
            int r = i >> 6, d = i & 63;
            Ws[r][d] = (r < 16) ? Wq_w[r * 64 + d] : Wk_w[(r - 16) * 64 + d];
        }
        if (tid < 32) bsm[tid] = (tid < 16) ? Wq_b[tid] : Wk_b[tid - 16];
        int row0 = bid * 8;
        for (int i = tid; i < 512; i += 256) {
            int r = i >> 6, d = i & 63;
            Xs[r][d] = X[(size_t)(row0 + r) * 64 + d];
        }
        __syncthreads();
        int r = tid >> 5;
        int j = tid & 31;
        float s = bsm[j];
        #pragma unroll
        for (int d = 0; d < 64; ++d) s = fmaf(Xs[r][d], Ws[j][d], s);
        int row = row0 + r;
        if (j < 16) {
            Q[(size_t)row * 16 + j] = s;
        } else {
            int h = (j - 16) >> 1, d2 = (j - 16) & 1;
            int b = row >> 10, l = row & 1023;
            K[(((size_t)(b * 8 + h)) * 1024 + l) * 2 + d2] = s;
        }
    } else if (bid < 1152) {
        // ---- XtP pack: chunk ((bb*32+lblk)*4+mi)*64+lane holds
        //      X[bb][lblk*32 + (lane>>4)*8 + j][mi*16 + (lane&15)], j=0..7
        int idx = bid - 1024;            // 0..127
        int bb = idx >> 4, lc = idx & 15;
        int l0 = lc * 64;
        int r = tid >> 4;                // 0..15
        int q4 = (tid & 15) * 4;
        #pragma unroll
        for (int p = 0; p < 4; ++p) {
            int row = p * 16 + r;
            float4 v = *(const float4*)(X + ((size_t)(bb * 1024 + l0 + row)) * 64 + q4);
            S[row][q4 + 0] = f2bf(v.x);
            S[row][q4 + 1] = f2bf(v.y);
            S[row][q4 + 2] = f2bf(v.z);
            S[row][q4 + 3] = f2bf(v.w);
        }
        __syncthreads();
        #pragma unroll
        for (int it = 0; it < 2; ++it) {
            int chunk = it * 256 + tid;
            int lane = chunk & 63, mi = (chunk >> 6) & 3, lbr = chunk >> 8;
            int g = lane >> 4, tr = lane & 15;
            int d = mi * 16 + tr;
            int ls = lbr * 32 + g * 8;
            u16x8 o;
            #pragma unroll
            for (int j = 0; j < 8; ++j) o[j] = S[ls + j][d];
            *(u16x8*)(XtP + (size_t)((((bb * 32 + lc * 2 + lbr) * 4 + mi) * 64 + lane)) * 8) = o;
        }
    } else {
        // ---- W_w -> bf16 ----
        int i = (bid - 1152) * 256 + tid;
        float4 v = ((const float4*)W_w)[i];
        ushort4 o;
        o.x = f2bf(v.x); o.y = f2bf(v.y); o.z = f2bf(v.z); o.w = f2bf(v.w);
        ((ushort4*)Wbf)[i] = o;
    }
}

// ---------------- Kernel B: scores + analytic-max softmax + MFMA PV ----------------
// grid (16 t-blocks, 8 h, 8 b), block 512 = 8 waves = 4 t-subtiles x 2 l-halves.
// X fragments staged per block via a 3-buffer global_load_lds pipeline with
// counted vmcnt (round-10-proven). Score math on packed v_pk_fma_f32; K stored
// in LDS as {x0,x1,y0,y1} pair-quads so pk operands load pre-paired.
__global__ __launch_bounds__(512, 8) void attn_mfma(const unsigned short* __restrict__ XtP,
                                                    const float* __restrict__ Q,
                                                    const float* __restrict__ K,
                                                    const float* __restrict__ u,
                                                    const float* __restrict__ Wkey,
                                                    const float* __restrict__ center,
                                                    const float* __restrict__ alpha,
                                                    unsigned short* __restrict__ IV) {
    const int h  = blockIdx.y;
    const int bb = blockIdx.z;
    const int tid = threadIdx.x;
    const int w = tid >> 6, lane = tid & 63;
    const int g = lane >> 4, tr = lane & 15;
    const int tsub = w & 3, lhalf = w >> 2;
    const int t = blockIdx.x * 64 + tsub * 16 + tr;

    __shared__ float Ks[2048];               // 8 KB: pair-quads {x0,x1,y0,y1} per 2 l's
    __shared__ unsigned short Xs[3][4096];   // 3 x 8 KB X-fragment buffers
    __shared__ float red[8][4];
    float* Cc = (float*)&Xs[0][0];           // post-loop combine overlay (17408B <= 24576B)

    // staging source: thread tid covers chunk (tid&255) of lblk {it | 16+it}
    const unsigned short* xsrc = XtP + (size_t)bb * 65536
                               + (size_t)((tid >> 8) * 16) * 2048 + (tid & 255) * 8;

    {   // K -> LDS, deinterleaved to pair-quads: {x(2s), x(2s+1), y(2s), y(2s+1)}
        const float4* Kg = (const float4*)(K + ((size_t)(bb * 8 + h)) * 2048);
        float4 kv = Kg[tid];                 // {x(2s), y(2s), x(2s+1), y(2s+1)}
        ((float4*)Ks)[tid] = make_float4(kv.x, kv.z, kv.y, kv.w);
    }
    __syncthreads();

    // block-wide K extrema for the analytic max bound
    float mxp, mxn, myp, myn;
    {
        float4 kk = ((const float4*)Ks)[tid];    // covers l = 2*tid, 2*tid+1
        mxp = fmaxf(kk.x, kk.y); mxn = fminf(kk.x, kk.y);
        myp = fmaxf(kk.z, kk.w); myn = fminf(kk.z, kk.w);
        #pragma unroll
        for (int off = 32; off; off >>= 1) {
            mxp = fmaxf(mxp, __shfl_xor(mxp, off)); mxn = fminf(mxn, __shfl_xor(mxn, off));
            myp = fmaxf(myp, __shfl_xor(myp, off)); myn = fminf(myn, __shfl_xor(myn, off));
        }
        if (lane == 0) { red[w][0] = mxp; red[w][1] = mxn; red[w][2] = myp; red[w][3] = myn; }
    }
    __syncthreads();
    mxp = red[0][0]; mxn = red[0][1]; myp = red[0][2]; myn = red[0][3];
    #pragma unroll
    for (int i = 1; i < 8; ++i) {
        mxp = fmaxf(mxp, red[i][0]); mxn = fminf(mxn, red[i][1]);
        myp = fmaxf(myp, red[i][2]); myn = fminf(myn, red[i][3]);
    }

    const float L2E = 1.4426950408889634f;
    float2 q  = ((const float2*)Q)[(size_t)(bb * 1024 + t) * 8 + h];
    float2 uu = ((const float2*)u)[t];
    const float al = alpha[0];
    const float a0 = (q.x + uu.x) * L2E;
    const float a1 = (q.y + uu.y) * L2E;
    const float p0 = q.x - al;
    const float p1 = q.y + 2.0f * al * center[h];
    const float c0 = (p0 * Wkey[0] + p1 * Wkey[2]) * L2E;
    const float c1 = (p0 * Wkey[1] + p1 * Wkey[3]) * L2E;
    const float tf = (float)t;

    // analytic upper bound on max score
    const float qb = fmaxf(a0 * mxp, a0 * mxn) + fmaxf(a1 * myp, a1 * myn);
    const float dlo = -tf, dhi = 1023.0f - tf;
    float qm = fmaxf(fmaf(fmaf(c0, dlo, c1), dlo, 0.0f),
                     fmaf(fmaf(c0, dhi, c1), dhi, 0.0f));
    if (c0 < 0.0f) {
        float dstar = -c1 / (2.0f * c0);
        if (dstar > dlo && dstar < dhi) qm = -c1 * c1 / (4.0f * c0);
    }
    const float negm = -(qm + qb);

    // packed constants for the score polynomial
    const f32x2 a0_2 = {a0, a0}, a1_2 = {a1, a1};
    const f32x2 c0_2 = {c0, c0}, c1_2 = {c1, c1};
    const f32x2 nm_2 = {negm, negm}, two2 = {2.0f, 2.0f};

    f32x4 acc[4];
    #pragma unroll
    for (int mi = 0; mi < 4; ++mi) acc[mi] = (f32x4){0.f, 0.f, 0.f, 0.f};
    float sum = 0.f;

#define XSTAGE(bufi, itx) \
    __builtin_amdgcn_global_load_lds((glb_u32*)(xsrc + (itx) * 2048), \
                                     (lds_u32*)(&Xs[bufi][tid * 8]), 16, 0, 0)

    XSTAGE(0, 0);
    XSTAGE(1, 1);

    #pragma unroll
    for (int it = 0; it < 16; ++it) {
        // Wait own stage-it load (1/thread), keep stage it+1 in flight.
        if (it < 15) asm volatile("s_waitcnt vmcnt(1)" ::: "memory");
        else         asm volatile("s_waitcnt vmcnt(0)" ::: "memory");
        __builtin_amdgcn_s_barrier();              // stage-it data visible block-wide
        __builtin_amdgcn_sched_barrier(0);         // no ds_read hoisted above barrier
        // Stage it+2 into buf (it+2)%3: last read at iter it-1, whose ds_reads
        // were register-consumed (lgkmcnt-waited by MFMAs) before this barrier.
        if (it < 14) XSTAGE((it + 2) % 3, it + 2);

        const int cur = it % 3;
        const int lb = lhalf * 512 + it * 32 + g * 8;
        const float4* kp = (const float4*)Ks + (lb >> 1);   // pair-quads
        f32x2 dl2 = {(float)lb - tf, (float)lb - tf + 1.0f};
        union { bf16x8 v; unsigned int wd[4]; } pb;
        #pragma unroll
        for (int jj = 0; jj < 4; ++jj) {
            float4 kv = kp[jj];                  // {x0,x1,y0,y1} for l = lb+2jj, +1
            f32x2 kx2 = {kv.x, kv.y};
            f32x2 ky2 = {kv.z, kv.w};
            f32x2 s2 = pk_fma(a1_2, ky2, nm_2);
            s2 = pk_fma(a0_2, kx2, s2);
            f32x2 q2 = pk_fma(c0_2, dl2, c1_2);
            s2 = pk_fma(q2, dl2, s2);
            dl2 = pk_add(dl2, two2);
            float e0 = exp2f(s2.x);
            float e1 = exp2f(s2.y);
            sum += e0 + e1;
            asm("v_cvt_pk_bf16_f32 %0, %1, %2" : "=v"(pb.wd[jj]) : "v"(e0), "v"(e1));
        }
        const bf16x8* xv = (const bf16x8*)(&Xs[cur][0]);
        #pragma unroll
        for (int mi = 0; mi < 4; ++mi)
            acc[mi] = __builtin_amdgcn_mfma_f32_16x16x32_bf16(
                xv[lhalf * 256 + mi * 64 + lane], pb.v, acc[mi], 0, 0, 0);
    }
#undef XSTAGE

    sum += __shfl_xor(sum, 16);
    sum += __shfl_xor(sum, 32);

    __syncthreads();                     // all reads of Xs done -> Cc overlay safe
    if (lhalf == 1) {
        float* cp = Cc + (tsub * 64 + lane) * 17;
        #pragma unroll
        for (int mi = 0; mi < 4; ++mi)
            #pragma unroll
            for (int r = 0; r < 4; ++r) cp[mi * 4 + r] = acc[mi][r];
        cp[16] = sum;
    }
    __syncthreads();
    if (lhalf == 0) {
        const float* cp = Cc + (tsub * 64 + lane) * 17;
        #pragma unroll
        for (int mi = 0; mi < 4; ++mi)
            #pragma unroll
            for (int r = 0; r < 4; ++r) acc[mi][r] += cp[mi * 4 + r];
        sum += cp[16];
        const float rinv = 1.0f / sum;
        #pragma unroll
        for (int mi = 0; mi < 4; ++mi) {
            #pragma unroll
            for (int r = 0; r < 4; ++r) {
                int d = mi * 16 + g * 4 + r;
                IV[((size_t)(bb * 512 + h * 64 + d)) * 1024 + t] = f2bf(acc[mi][r] * rinv);
            }
        }
    }
}

// ---------------- Kernel C: out = IV @ W_w^T + W_b ----------------
// Fused M=4096, tile 128m x 128n, BK=32, 4-buffer global_load_lds pipeline with
// counted vmcnt + one raw s_barrier per K-step (round-9/10-proven).
// Grid now (32 mt, 8 jt): XCD = linear%8 = mt%8 -> per-XCD working set =
// 4 IV panels (1MB) + Wbf (2MB) = 3MB, L2-resident; L3 traffic 64->24 MB.
// block 512 = 8 waves, wave 64x32.
__global__ __launch_bounds__(512) void gemm_out(const unsigned short* __restrict__ IV,
                                                const unsigned short* __restrict__ Wbf,
                                                const float* __restrict__ W_b,
                                                float* __restrict__ out) {
    const int mt = blockIdx.x;      // 0..31 (128 rows each)  [XCD-locality: mt%8]
    const int jt = blockIdx.y;      // 0..7  (128 cols each)
    const int tid = threadIdx.x;
    const int w = tid >> 6, lane = tid & 63;
    const int lr = lane & 15, kg = lane >> 4;
    const int wr = w >> 2, wc = w & 3;      // wave tile: rows wr*64, cols wc*32

    __shared__ unsigned short As[4][8192];   // 4 x 8KB  (128 rows x 32 k)
    __shared__ unsigned short Bs[4][8192];   // 4 x 8KB

    // staging: thread tid covers chunk (row=tid>>2, phys slot=tid&3);
    // kg_written = slot ^ ((row>>1)&3)  (same involution as read side).
    const int r0 = tid >> 2, s0 = tid & 3;   // r0 0..127
    const int kga = s0 ^ ((r0 >> 1) & 3);
    const unsigned short* Ag = IV  + (size_t)(mt * 128 + r0) * 1024 + kga * 8;
    const unsigned short* Bg = Wbf + (size_t)(jt * 128 + r0) * 1024 + kga * 8;

#define STAGE(bufi, kk) do {                                                                           \
    __builtin_amdgcn_global_load_lds((glb_u32*)(Ag + (kk)), (lds_u32*)(&As[bufi][tid * 8]), 16, 0, 0); \
    __builtin_amdgcn_global_load_lds((glb_u32*)(Bg + (kk)), (lds_u32*)(&Bs[bufi][tid * 8]), 16, 0, 0); \
} while (0)

    f32x4 acc[4][2];
    #pragma unroll
    for (int mi = 0; mi < 4; ++mi)
        #pragma unroll
        for (int ni = 0; ni < 2; ++ni)
            acc[mi][ni] = (f32x4){0.f, 0.f, 0.f, 0.f};

    STAGE(0, 0);
    STAGE(1, 32);
    STAGE(2, 64);

    const int slot = kg ^ ((lr >> 1) & 3);        // read-side involution (matches write)

    #pragma unroll
    for (int kt = 0; kt < 32; ++kt) {
        // Wait own stage-kt loads (2/wave), keep stages kt+1,kt+2 (4) in flight.
        if (kt < 30)       asm volatile("s_waitcnt vmcnt(4)" ::: "memory");
        else if (kt == 30) asm volatile("s_waitcnt vmcnt(2)" ::: "memory");
        else               asm volatile("s_waitcnt vmcnt(0)" ::: "memory");
        __builtin_amdgcn_s_barrier();              // all waves' stage-kt data visible
        __builtin_amdgcn_sched_barrier(0);         // pin: no ds_read hoisted above barrier
        // Issue stage kt+3 into buf (kt+3)&3 == (kt-1)&3 -- last read at iter kt-1,
        // whose ds_reads were consumed (lgkmcnt-waited by MFMAs) before this barrier.
        if (kt < 29) STAGE((kt + 3) & 3, (kt + 3) * 32);

        const int cur = kt & 3;
        bf16x8 af[4], bfr[2];
        #pragma unroll
        for (int mi = 0; mi < 4; ++mi) {
            int row = wr * 64 + mi * 16 + lr;
            af[mi] = *(const bf16x8*)(&As[cur][row * 32 + slot * 8]);
        }
        #pragma unroll
        for (int ni = 0; ni < 2; ++ni) {
            int row = wc * 32 + ni * 16 + lr;
            bfr[ni] = *(const bf16x8*)(&Bs[cur][row * 32 + slot * 8]);
        }
        #pragma unroll
        for (int mi = 0; mi < 4; ++mi)
            #pragma unroll
            for (int ni = 0; ni < 2; ++ni)
                acc[mi][ni] = __builtin_amdgcn_mfma_f32_16x16x32_bf16(
                    af[mi], bfr[ni], acc[mi][ni], 0, 0, 0);
    }
#undef STAGE

    float wb[2];
    #pragma unroll
    for (int ni = 0; ni < 2; ++ni) wb[ni] = W_b[jt * 128 + wc * 32 + ni * 16 + lr];

    #pragma unroll
    for (int mi = 0; mi < 4; ++mi) {
        #pragma unroll
        for (int ni = 0; ni < 2; ++ni) {
            #pragma unroll
            for (int r = 0; r < 4; ++r) {
                int m = mt * 128 + wr * 64 + mi * 16 + kg * 4 + r;   // fused row b*512+c
                int j = jt * 128 + wc * 32 + ni * 16 + lr;
                out[(size_t)m * 1024 + j] = acc[mi][ni][r] + wb[ni];
            }
        }
    }
}

extern "C" void kernel_launch(void* const* d_in, const int* in_sizes, int n_in,
                              void* d_out, int out_size, void* d_ws, size_t ws_size,
                              hipStream_t stream) {
    const float* X      = (const float*)d_in[0];
    const float* Wq_w   = (const float*)d_in[1];
    const float* Wq_b   = (const float*)d_in[2];
    const float* Wk_w   = (const float*)d_in[3];
    const float* Wk_b   = (const float*)d_in[4];
    const float* Wkey   = (const float*)d_in[5];
    const float* u      = (const float*)d_in[6];
    // d_in[7] = R : analytically reconstructed, never read
    const float* center = (const float*)d_in[8];
    const float* alpha  = (const float*)d_in[9];
    const float* W_w    = (const float*)d_in[10];
    const float* W_b    = (const float*)d_in[11];
    float* out = (float*)d_out;

    // Workspace layout (12 MB, no aliasing; proven ws_size >= 12.25 MB):
    //   0..1 MB   : XtP (bf16 packed fragments)
    //   1..1.5 MB : Q
    //   1.5..2 MB : K
    //   2..4 MB   : Wbf
    //   4..12 MB  : IV
    char* ws = (char*)d_ws;
    unsigned short* XtP  = (unsigned short*)ws;                      // 1 MB
    float*          Qbuf = (float*)(ws + (1024u << 10));             // 512 KB
    float*          Kbuf = (float*)(ws + (1536u << 10));             // 512 KB
    unsigned short* Wbf  = (unsigned short*)(ws + (2048u << 10));    // 2 MB
    unsigned short* IV   = (unsigned short*)(ws + (4096u << 10));    // 8 MB

    prep_fused<<<2176, 256, 0, stream>>>(X, Wq_w, Wq_b, Wk_w, Wk_b, W_w, Qbuf, Kbuf, XtP, Wbf);
    attn_mfma<<<dim3(16, 8, 8), 512, 0, stream>>>(XtP, Qbuf, Kbuf, u, Wkey, center, alpha, IV);
    gemm_out<<<dim3(32, 8), 512, 0, stream>>>(IV, Wbf, W_b, out);
}